// Round 1
// baseline (374.105 us; speedup 1.0000x reference)
//
#include <hip/hip_runtime.h>

// Problem constants
#define K_CODES 512
#define DIM 64
#define HW 1024          // 32*32 spatial per image
#define NVEC 65536       // 64 * 1024 flat vectors

// Output offsets (flat concat, reference return order)
#define O0 0             // loss (1)
#define O1 1             // out_q NCHW (4194304)
#define O2 4194305       // perplexity (1)
#define O3 4194306       // idx as float (65536)
#define O4 4259842       // new_cs (512)
#define O5 4260354       // new_ema_w (32768)
#define O6 4293122       // new_embedding (32768)

// Workspace layout (floats): [0]=loss accum, [64..576)=ee, [1024..1536)=counts(int), [2048..34816)=dw

__global__ void k0_init(const float* __restrict__ emb, float* __restrict__ wsf) {
    const int b = blockIdx.x, t = threadIdx.x;
    if (b < 128) {
        wsf[2048 + b * 256 + t] = 0.0f;                 // zero dw accumulator
    } else if (b == 128) {
        int* cnt = (int*)(wsf + 1024);
        cnt[t] = 0; cnt[t + 256] = 0;
        if (t == 0) wsf[0] = 0.0f;                      // zero loss accum
    } else {
        int k = (b - 129) * 256 + t;                    // 0..511
        const float* e = emb + k * DIM;
        float s = 0.0f;
        #pragma unroll
        for (int c = 0; c < DIM; ++c) s += e[c] * e[c];
        wsf[64 + k] = s;                                // ||e_k||^2
    }
}

__launch_bounds__(256)
__global__ void k1_main(const float* __restrict__ in, const float* __restrict__ emb,
                        float* __restrict__ out, float* __restrict__ wsf) {
    __shared__ float xT[256 * 65];   // padded stride 65 -> conflict-free transpose
    __shared__ int   sidx[256];
    __shared__ int   hist[K_CODES];

    const int t  = threadIdx.x;
    const int i  = blockIdx.x * 256 + t;   // flat vector index
    const int n  = i >> 10;
    const int hw = i & 1023;

    hist[t] = 0; hist[t + 256] = 0;

    // Load x[64] (coalesced across lanes per c-plane), build LDS transpose, xx
    const float* xb = in + n * (DIM * HW) + hw;
    float x[DIM];
    float xx = 0.0f;
    #pragma unroll
    for (int c = 0; c < DIM; ++c) {
        float v = xb[c * HW];
        x[c] = v;
        xT[t * 65 + c] = v;
        xx += v * v;
    }

    // Distance + argmin: d_k = ||e_k||^2 - 2<x,e_k>  (xx constant, dropped)
    const float* ee = wsf + 64;
    float best = 3.4e38f;
    int bidx = 0;
    for (int k = 0; k < K_CODES; k += 4) {
        const float* e0 = emb + k * DIM;   // wave-uniform address -> s_load broadcast
        float d0 = 0.f, d1 = 0.f, d2 = 0.f, d3 = 0.f;
        #pragma unroll
        for (int c = 0; c < DIM; ++c) {
            float xc = x[c];
            d0 += xc * e0[c];
            d1 += xc * e0[c + 64];
            d2 += xc * e0[c + 128];
            d3 += xc * e0[c + 192];
        }
        float t0 = ee[k + 0] - 2.0f * d0;
        float t1 = ee[k + 1] - 2.0f * d1;
        float t2 = ee[k + 2] - 2.0f * d2;
        float t3 = ee[k + 3] - 2.0f * d3;
        if (t0 < best) { best = t0; bidx = k + 0; }   // strict <, ascending k ->
        if (t1 < best) { best = t1; bidx = k + 1; }   // first-min, matches argmin
        if (t2 < best) { best = t2; bidx = k + 2; }
        if (t3 < best) { best = t3; bidx = k + 3; }
    }
    sidx[t] = bidx;
    __syncthreads();

    // counts histogram (LDS)
    atomicAdd(&hist[bidx], 1);

    // loss partial: d_min = xx + best ; wave shuffle-reduce -> 1 atomic per wave
    float ld = xx + best;
    #pragma unroll
    for (int off = 32; off > 0; off >>= 1) ld += __shfl_down(ld, off);
    if ((t & 63) == 0) atomicAdd(wsf + 0, ld);

    // out_q (NCHW): coalesced stores per c-plane; gather from L2-resident codebook
    const float* ew = emb + bidx * DIM;
    float* oq = out + O1 + n * (DIM * HW) + hw;
    #pragma unroll
    for (int c = 0; c < DIM; ++c) oq[c * HW] = ew[c];

    // idx output (as float)
    out[O3 + i] = (float)bidx;

    __syncthreads();

    // flush histogram to global counts
    int* cnt = (int*)(wsf + 1024);
    if (hist[t])       atomicAdd(&cnt[t], hist[t]);
    if (hist[t + 256]) atomicAdd(&cnt[t + 256], hist[t + 256]);

    // dw: wave-per-vector, coalesced 64-lane atomic row add (256B, L2-resident)
    float* dw = wsf + 2048;
    const int wave = t >> 6, lane = t & 63;
    #pragma unroll 1
    for (int v = wave * 64; v < wave * 64 + 64; ++v) {
        int   kv = sidx[v];
        float xv = xT[v * 65 + lane];
        atomicAdd(&dw[kv * DIM + lane], xv);
    }
}

__global__ void k2a(const float* __restrict__ ema_cs, float* __restrict__ out,
                    const float* __restrict__ wsf) {
    __shared__ float s1[512], s2[512];
    const int t = threadIdx.x;
    const int* cnt = (const int*)(wsf + 1024);
    float c   = (float)cnt[t];
    float raw = 0.99f * ema_cs[t] + 0.01f * c;
    float p   = c * (1.0f / 65536.0f);
    s1[t] = raw;
    s2[t] = p * logf(p + 1e-10f);
    __syncthreads();
    for (int s = 256; s > 0; s >>= 1) {
        if (t < s) { s1[t] += s1[t + s]; s2[t] += s2[t + s]; }
        __syncthreads();
    }
    float n = s1[0];
    float smooth = (raw + 1e-5f) / (n + 512.0f * 1e-5f) * n;   // Laplace smoothing
    out[O4 + t] = smooth;
    if (t == 0) {
        out[O2] = expf(-s2[0]);
        out[O0] = 0.25f * wsf[0] * (1.0f / 4194304.0f);        // BETA * mean
    }
}

__global__ void k2b(const float* __restrict__ ema_w, const float* __restrict__ wsf,
                    float* __restrict__ out) {
    const int m = blockIdx.x * 256 + threadIdx.x;   // 0..32767
    const int k = m >> 6;
    float w = 0.99f * ema_w[m] + 0.01f * wsf[2048 + m];
    out[O5 + m] = w;
    out[O6 + m] = w / out[O4 + k];                  // new_embedding = new_ema_w / new_cs
}

extern "C" void kernel_launch(void* const* d_in, const int* in_sizes, int n_in,
                              void* d_out, int out_size, void* d_ws, size_t ws_size,
                              hipStream_t stream) {
    const float* in     = (const float*)d_in[0];   // inputs  (64,64,32,32) NCHW
    const float* emb    = (const float*)d_in[1];   // embedding (512,64)
    const float* ema_w  = (const float*)d_in[2];   // ema_w (512,64)
    const float* ema_cs = (const float*)d_in[3];   // ema_cluster_size (512)
    float* out = (float*)d_out;
    float* wsf = (float*)d_ws;

    hipLaunchKernelGGL(k0_init, dim3(131), dim3(256), 0, stream, emb, wsf);
    hipLaunchKernelGGL(k1_main, dim3(256), dim3(256), 0, stream, in, emb, out, wsf);
    hipLaunchKernelGGL(k2a,     dim3(1),   dim3(512), 0, stream, ema_cs, out, wsf);
    hipLaunchKernelGGL(k2b,     dim3(128), dim3(256), 0, stream, ema_w, wsf, out);
}